// Round 4
// baseline (201.586 us; speedup 1.0000x reference)
//
#include <hip/hip_runtime.h>

#define D 256
#define NBLOCKS 2048
#define WPB 4
#define NT 256

__global__ __launch_bounds__(NT, 8) void gc_fused(
    const float* __restrict__ feat,
    const int* __restrict__ known,
    const int* __restrict__ unknown,
    float* __restrict__ acc,            // [3*D] column partial sums
    unsigned int* __restrict__ ticket,  // last-block ticket
    float* __restrict__ out,
    int N)
{
    const int lane = threadIdx.x & 63;
    const int wave = threadIdx.x >> 6;
    const int gw   = blockIdx.x * WPB + wave;
    const int nw   = gridDim.x * WPB;

    float4 aAll = {0.f,0.f,0.f,0.f};
    float4 aK   = {0.f,0.f,0.f,0.f};
    float4 aU   = {0.f,0.f,0.f,0.f};

    int row = gw;
    if (row < N) {
        const float4* rp = (const float4*)(feat + (size_t)row * D);
        float4 v = rp[lane];            // 16B/lane x 64 lanes = full 1KB row
        int kn = known[row];
        int un = unknown[row];
        for (;;) {
            // ---- prefetch next row before the dependent reduce chain ----
            const int nrow = row + nw;
            const bool more = (nrow < N);   // wave-uniform
            float4 vn = {0.f,0.f,0.f,0.f};
            int knn = 0, unn = 0;
            if (more) {
                const float4* rpn = (const float4*)(feat + (size_t)nrow * D);
                vn  = rpn[lane];
                knn = known[nrow];
                unn = unknown[nrow];
            }
            // ---- current row: norm, scale, accumulate ----
            float ss = v.x*v.x + v.y*v.y + v.z*v.z + v.w*v.w;
            #pragma unroll
            for (int off = 32; off > 0; off >>= 1)
                ss += __shfl_xor(ss, off);
            float inv = rsqrtf(fmaxf(ss, 1e-16f));   // norms ~16, eps moot
            float ux = v.x*inv, uy = v.y*inv, uz = v.z*inv, uw = v.w*inv;
            aAll.x += ux; aAll.y += uy; aAll.z += uz; aAll.w += uw;
            if (kn) { aK.x += ux; aK.y += uy; aK.z += uz; aK.w += uw; }
            if (un) { aU.x += ux; aU.y += uy; aU.z += uz; aU.w += uw; }
            if (!more) break;
            v = vn; kn = knn; un = unn; row = nrow;
        }
    }

    // ---- block reduce: wave writes 256-col partial; 256 threads sum cols ----
    __shared__ float red[WPB][D];
    float4 accs[3] = {aAll, aK, aU};
    #pragma unroll
    for (int a = 0; a < 3; ++a) {
        float4 t = accs[a];
        red[wave][lane * 4 + 0] = t.x;
        red[wave][lane * 4 + 1] = t.y;
        red[wave][lane * 4 + 2] = t.z;
        red[wave][lane * 4 + 3] = t.w;
        __syncthreads();
        const int col = threadIdx.x;
        float s = red[0][col] + red[1][col] + red[2][col] + red[3][col];
        atomicAdd(acc + a * D + col, s);
        __syncthreads();
    }

    // ---- last-block finalization (replaces gc_final launch) ----
    __shared__ int is_last;
    __threadfence();                       // make our acc atomics visible
    if (threadIdx.x == 0) {
        unsigned int t = atomicAdd(ticket, 1u);
        is_last = (t == (unsigned int)gridDim.x - 1u);
    }
    __syncthreads();
    if (is_last) {
        const int d = threadIdx.x;
        // read at the coherent point (all blocks' adds are visible by ticket order)
        float sa = atomicAdd(acc + d,         0.0f);
        float sk = atomicAdd(acc + D + d,     0.0f);
        float su = atomicAdd(acc + 2 * D + d, 0.0f);
        float p1 = sa * sk;
        float p2 = sk * sk;
        float p3 = sk * su;
        #pragma unroll
        for (int off = 32; off > 0; off >>= 1) {
            p1 += __shfl_xor(p1, off);
            p2 += __shfl_xor(p2, off);
            p3 += __shfl_xor(p3, off);
        }
        __shared__ float r[3][WPB];
        if (lane == 0) { r[0][wave] = p1; r[1][wave] = p2; r[2][wave] = p3; }
        __syncthreads();
        if (threadIdx.x == 0) {
            float t1 = r[0][0] + r[0][1] + r[0][2] + r[0][3];
            float t2 = r[1][0] + r[1][1] + r[1][2] + r[1][3];
            float t3 = r[2][0] + r[2][1] + r[2][2] + r[2][3];
            float gain = t1 - 0.5f * t2 - t3;   // LAMDA=0.5, ETA=1.0
            out[0] = -gain / (float)N;
        }
    }
}

extern "C" void kernel_launch(void* const* d_in, const int* in_sizes, int n_in,
                              void* d_out, int out_size, void* d_ws, size_t ws_size,
                              hipStream_t stream) {
    const float* feat    = (const float*)d_in[0];
    const int*   known   = (const int*)d_in[1];
    const int*   unknown = (const int*)d_in[2];
    const int N = in_sizes[1];

    float* acc = (float*)d_ws;                          // 3*D floats
    unsigned int* ticket = (unsigned int*)((char*)d_ws + 3 * D * sizeof(float));

    hipMemsetAsync(d_ws, 0, 3 * D * sizeof(float) + sizeof(unsigned int), stream);
    gc_fused<<<NBLOCKS, NT, 0, stream>>>(feat, known, unknown, acc, ticket,
                                         (float*)d_out, N);
}

// Round 5
// 91.556 us; speedup vs baseline: 2.2018x; 2.2018x over previous
//
#include <hip/hip_runtime.h>

#define D 256
#define NBLOCKS 1024
#define WPB 4
#define EPS 1e-8f

// Stage 1: stream rows, per-block partial column sums -> plain stores (no atomics)
__global__ __launch_bounds__(256) void gc_partial(
    const float* __restrict__ feat,
    const int* __restrict__ known,
    const int* __restrict__ unknown,
    float* __restrict__ partials,   // [NBLOCKS][3*D]
    int N)
{
    const int lane = threadIdx.x & 63;
    const int wave = threadIdx.x >> 6;
    const int gw   = blockIdx.x * WPB + wave;
    const int nw   = gridDim.x * WPB;

    float4 aAll = {0.f, 0.f, 0.f, 0.f};
    float4 aK   = {0.f, 0.f, 0.f, 0.f};
    float4 aU   = {0.f, 0.f, 0.f, 0.f};

    for (int row = gw; row < N; row += nw) {
        const float4* rp = (const float4*)(feat + (size_t)row * D);
        float4 v = rp[lane];                       // 16B/lane x 64 lanes = full row
        float ss = v.x * v.x + v.y * v.y + v.z * v.z + v.w * v.w;
        #pragma unroll
        for (int off = 32; off > 0; off >>= 1)
            ss += __shfl_xor(ss, off);             // wave64 reduce
        float inv = 1.0f / fmaxf(sqrtf(ss), EPS);
        float4 u = {v.x * inv, v.y * inv, v.z * inv, v.w * inv};

        aAll.x += u.x; aAll.y += u.y; aAll.z += u.z; aAll.w += u.w;
        const bool kn = known[row] != 0;           // int32 masks, wave-uniform
        const bool un = unknown[row] != 0;
        if (kn) { aK.x += u.x; aK.y += u.y; aK.z += u.z; aK.w += u.w; }
        if (un) { aU.x += u.x; aU.y += u.y; aU.z += u.z; aU.w += u.w; }
    }

    // block reduce: wave writes its 256-col partial; 256 threads sum columns
    __shared__ float red[WPB][D];
    float* pout = partials + (size_t)blockIdx.x * (3 * D);
    float4 accs[3] = {aAll, aK, aU};
    #pragma unroll
    for (int a = 0; a < 3; ++a) {
        float4 t = accs[a];
        red[wave][lane * 4 + 0] = t.x;
        red[wave][lane * 4 + 1] = t.y;
        red[wave][lane * 4 + 2] = t.z;
        red[wave][lane * 4 + 3] = t.w;
        __syncthreads();
        const int col = threadIdx.x;
        float s = red[0][col] + red[1][col] + red[2][col] + red[3][col];
        pout[a * D + col] = s;                     // plain coalesced store
        __syncthreads();
    }
}

// Stage 2: one block, 768 threads; column-sum partials then finalize
__global__ __launch_bounds__(768) void gc_final(
    const float* __restrict__ partials, float* __restrict__ out, int N)
{
    const int t = threadIdx.x;                     // 0..767
    float s = 0.f;
    // coalesced: consecutive t -> consecutive addresses each iteration
    #pragma unroll 8
    for (int b = 0; b < NBLOCKS; ++b)
        s += partials[(size_t)b * (3 * D) + t];

    __shared__ float ls[3 * D];
    ls[t] = s;
    __syncthreads();

    if (t < D) {
        const float sa = ls[t];
        const float sk = ls[D + t];
        const float su = ls[2 * D + t];
        float p1 = sa * sk;
        float p2 = sk * sk;
        float p3 = sk * su;
        #pragma unroll
        for (int off = 32; off > 0; off >>= 1) {
            p1 += __shfl_xor(p1, off);
            p2 += __shfl_xor(p2, off);
            p3 += __shfl_xor(p3, off);
        }
        __shared__ float r[3][4];
        const int wave = t >> 6, lane = t & 63;
        if (lane == 0) { r[0][wave] = p1; r[1][wave] = p2; r[2][wave] = p3; }
        __syncthreads();
        if (t == 0) {
            float t1 = r[0][0] + r[0][1] + r[0][2] + r[0][3];
            float t2 = r[1][0] + r[1][1] + r[1][2] + r[1][3];
            float t3 = r[2][0] + r[2][1] + r[2][2] + r[2][3];
            float gain = t1 - 0.5f * t2 - t3;      // LAMDA=0.5, ETA=1.0
            out[0] = -gain / (float)N;
        }
    }
}

extern "C" void kernel_launch(void* const* d_in, const int* in_sizes, int n_in,
                              void* d_out, int out_size, void* d_ws, size_t ws_size,
                              hipStream_t stream) {
    const float* feat    = (const float*)d_in[0];
    const int*   known   = (const int*)d_in[1];
    const int*   unknown = (const int*)d_in[2];
    const int N = in_sizes[1];
    float* partials = (float*)d_ws;                // NBLOCKS * 3*D floats (3 MB)

    gc_partial<<<NBLOCKS, 256, 0, stream>>>(feat, known, unknown, partials, N);
    gc_final<<<1, 768, 0, stream>>>(partials, (float*)d_out, N);
}

// Round 6
// 42.466 us; speedup vs baseline: 4.7470x; 2.1560x over previous
//
#include <hip/hip_runtime.h>

#define D 256
#define NBLOCKS 1024
#define WPB 4
#define EPS 1e-8f
#define NB2 64          // stage-2a blocks; NBLOCKS / NB2 rows each
#define ROWS2 (NBLOCKS / NB2)

// ---------------- Stage 1: stream rows, per-block partial column sums ----------------
__global__ __launch_bounds__(256) void gc_partial(
    const float* __restrict__ feat,
    const int* __restrict__ known,
    const int* __restrict__ unknown,
    float* __restrict__ partials,   // [NBLOCKS][3*D]
    int N)
{
    const int lane = threadIdx.x & 63;
    const int wave = threadIdx.x >> 6;
    const int gw   = blockIdx.x * WPB + wave;
    const int nw   = gridDim.x * WPB;

    float4 aAll = {0.f, 0.f, 0.f, 0.f};
    float4 aK   = {0.f, 0.f, 0.f, 0.f};
    float4 aU   = {0.f, 0.f, 0.f, 0.f};

    // 2 rows per wave-iteration: 2 independent 1KB loads in flight,
    // 2 interleaved shuffle-reduce chains. ~40 VGPR (stays in the <64 band).
    for (int r = gw * 2; r < N; r += nw * 2) {
        const int r1 = r + 1;
        const bool has2 = (r1 < N);                // wave-uniform; N even -> always true
        const float4* rp = (const float4*)(feat + (size_t)r * D);
        float4 v0 = rp[lane];
        float4 v1 = {0.f, 0.f, 0.f, 0.f};
        int kn0 = known[r],  un0 = unknown[r];
        int kn1 = 0, un1 = 0;
        if (has2) {
            v1  = rp[64 + lane];
            kn1 = known[r1];
            un1 = unknown[r1];
        }

        float s0 = v0.x*v0.x + v0.y*v0.y + v0.z*v0.z + v0.w*v0.w;
        float s1 = v1.x*v1.x + v1.y*v1.y + v1.z*v1.z + v1.w*v1.w;
        #pragma unroll
        for (int off = 32; off > 0; off >>= 1) {   // interleaved chains
            s0 += __shfl_xor(s0, off);
            s1 += __shfl_xor(s1, off);
        }
        float i0 = 1.0f / fmaxf(sqrtf(s0), EPS);
        float i1 = 1.0f / fmaxf(sqrtf(s1), EPS);

        float ux0 = v0.x*i0, uy0 = v0.y*i0, uz0 = v0.z*i0, uw0 = v0.w*i0;
        float ux1 = v1.x*i1, uy1 = v1.y*i1, uz1 = v1.z*i1, uw1 = v1.w*i1;

        aAll.x += ux0 + ux1; aAll.y += uy0 + uy1;
        aAll.z += uz0 + uz1; aAll.w += uw0 + uw1;
        if (kn0) { aK.x += ux0; aK.y += uy0; aK.z += uz0; aK.w += uw0; }
        if (kn1) { aK.x += ux1; aK.y += uy1; aK.z += uz1; aK.w += uw1; }
        if (un0) { aU.x += ux0; aU.y += uy0; aU.z += uz0; aU.w += uw0; }
        if (un1) { aU.x += ux1; aU.y += uy1; aU.z += uz1; aU.w += uw1; }
    }

    // block reduce: wave writes its 256-col partial; 256 threads sum columns
    __shared__ float red[WPB][D];
    float* pout = partials + (size_t)blockIdx.x * (3 * D);
    float4 accs[3] = {aAll, aK, aU};
    #pragma unroll
    for (int a = 0; a < 3; ++a) {
        float4 t = accs[a];
        red[wave][lane * 4 + 0] = t.x;
        red[wave][lane * 4 + 1] = t.y;
        red[wave][lane * 4 + 2] = t.z;
        red[wave][lane * 4 + 3] = t.w;
        __syncthreads();
        const int col = threadIdx.x;
        float s = red[0][col] + red[1][col] + red[2][col] + red[3][col];
        pout[a * D + col] = s;                     // plain coalesced store
        __syncthreads();
    }
}

// ---------------- Stage 2a: 64 blocks sum 16 partial rows each ----------------
__global__ __launch_bounds__(768) void gc_reduce1(
    const float* __restrict__ partials,   // [NBLOCKS][768]
    float* __restrict__ partials2)        // [NB2][768]
{
    const int t = threadIdx.x;            // 0..767, coalesced across columns
    const float* base = partials + (size_t)blockIdx.x * ROWS2 * (3 * D) + t;
    float s = 0.f;
    #pragma unroll
    for (int i = 0; i < ROWS2; ++i)
        s += base[(size_t)i * (3 * D)];
    partials2[(size_t)blockIdx.x * (3 * D) + t] = s;
}

// ---------------- Stage 2b: 1 block sums 64 rows, finalizes ----------------
__global__ __launch_bounds__(768) void gc_final(
    const float* __restrict__ partials2, float* __restrict__ out, int N)
{
    const int t = threadIdx.x;
    float s = 0.f;
    #pragma unroll
    for (int i = 0; i < NB2; ++i)
        s += partials2[(size_t)i * (3 * D) + t];

    __shared__ float ls[3 * D];
    ls[t] = s;
    __syncthreads();

    if (t < D) {
        const float sa = ls[t];
        const float sk = ls[D + t];
        const float su = ls[2 * D + t];
        float p1 = sa * sk;
        float p2 = sk * sk;
        float p3 = sk * su;
        #pragma unroll
        for (int off = 32; off > 0; off >>= 1) {
            p1 += __shfl_xor(p1, off);
            p2 += __shfl_xor(p2, off);
            p3 += __shfl_xor(p3, off);
        }
        __shared__ float r[3][4];
        const int wave = t >> 6, lane = t & 63;
        if (lane == 0) { r[0][wave] = p1; r[1][wave] = p2; r[2][wave] = p3; }
        __syncthreads();
        if (t == 0) {
            float t1 = r[0][0] + r[0][1] + r[0][2] + r[0][3];
            float t2 = r[1][0] + r[1][1] + r[1][2] + r[1][3];
            float t3 = r[2][0] + r[2][1] + r[2][2] + r[2][3];
            float gain = t1 - 0.5f * t2 - t3;      // LAMDA=0.5, ETA=1.0
            out[0] = -gain / (float)N;
        }
    }
}

extern "C" void kernel_launch(void* const* d_in, const int* in_sizes, int n_in,
                              void* d_out, int out_size, void* d_ws, size_t ws_size,
                              hipStream_t stream) {
    const float* feat    = (const float*)d_in[0];
    const int*   known   = (const int*)d_in[1];
    const int*   unknown = (const int*)d_in[2];
    const int N = in_sizes[1];

    float* partials  = (float*)d_ws;                                   // 3 MB
    float* partials2 = (float*)((char*)d_ws + (size_t)NBLOCKS * 3 * D * sizeof(float));

    gc_partial<<<NBLOCKS, 256, 0, stream>>>(feat, known, unknown, partials, N);
    gc_reduce1<<<NB2, 768, 0, stream>>>(partials, partials2);
    gc_final<<<1, 768, 0, stream>>>(partials2, (float*)d_out, N);
}